// Round 8
// baseline (1099.128 us; speedup 1.0000x reference)
//
#include <hip/hip_runtime.h>
#include <math.h>

#define Q 2048
#define NOBS 8192

// ---------------------------------------------------------------------------
// readlane broadcast: lane index is a compile-time literal after unrolling,
// so this is a VALU->SGPR read (no LDS/ds_bpermute 120cy latency).
__device__ __forceinline__ float rl(float v, int l) {
  return __int_as_float(__builtin_amdgcn_readlane(__float_as_int(v), l));
}

// ---------------------------------------------------------------------------
__device__ __forceinline__ float block_sum256(float v, volatile float* red) {
  int tid = threadIdx.x;
#pragma unroll
  for (int o = 32; o > 0; o >>= 1) v += __shfl_down(v, o);
  __syncthreads();
  if ((tid & 63) == 0) red[tid >> 6] = v;
  __syncthreads();
  return red[0] + red[1] + red[2] + red[3];
}

// ---------------------------------------------------------------------------
// In-register 64x64 Cholesky, one wave, lane = row. Broadcasts via readlane.
// rr[64] MUST stay in VGPRs (spill = 25x slowdown, measured round 3).
__device__ __forceinline__ float chol64_reg(float rr[64], int lane) {
  float dv = 1.0f;
#pragma unroll
  for (int j = 0; j < 64; ++j) {
    float vjj = rl(rr[j], j);
    float invd = rsqrtf(vjj);
    float lij = rr[j] * invd;   // lane j gets sqrt(vjj)
    rr[j] = lij;
    if (lane == j) dv = lij;
#pragma unroll
    for (int k = j + 1; k < 64; ++k) rr[k] -= lij * rl(lij, k);
  }
  return dv;
}

// ---------------------------------------------------------------------------
__global__ __launch_bounds__(256) void obs_kernel(
    const float* __restrict__ yt, const float* __restrict__ yp,
    const int* __restrict__ zidx, const float* __restrict__ s2e_p,
    const float* __restrict__ s2b_p, float* __restrict__ t,
    int* __restrict__ cnt, float* __restrict__ scal) {
  __shared__ float red[4];
  int i = blockIdx.x * 256 + threadIdx.x;
  float s2e = s2e_p[0], s2b = s2b_p[0];
  float sig2 = s2e + s2b;
  float r = yt[i] - yp[i];
  float e = erff(r * rsqrtf(2.0f * sig2));
  float u = 0.5f * (e + 1.0f);
  u = fminf(fmaxf(u, 1e-5f), 1.0f - 1e-5f);
  float m = erfinvf(2.0f * u - 1.0f) * 1.4142135623730951f;
  float slp = -0.5f * logf(2.0f * 3.14159265358979f * sig2) - r * r / (2.0f * sig2);
  int z = zidx[i];
  atomicAdd(&t[z], m);
  atomicAdd(&cnt[z], 1);
  float s1 = block_sum256(slp, red);
  float s2 = block_sum256(m * m, red);
  if (threadIdx.x == 0) {
    atomicAdd(&scal[0], s1);   // sum_log_pdf
    atomicAdd(&scal[1], s2);   // m'm
  }
}

// ---------------------------------------------------------------------------
// Fused: build G row j AND the matvec w = K t in one pass over dist row j.
__global__ __launch_bounds__(256) void build_mv(
    const float* __restrict__ dist, const float* __restrict__ s2e_p,
    const float* __restrict__ s2b_p, const float* __restrict__ ell_p,
    const int* __restrict__ cnt, const float* __restrict__ t,
    float* __restrict__ G, float* __restrict__ z, float* __restrict__ scal) {
  __shared__ float red[4];
  int j = blockIdx.x;
  float s2e = s2e_p[0], s2b = s2b_p[0], ell = ell_p[0];
  float sig2 = s2e + s2b;
  float ratio = s2b / sig2;
  float diag = s2e / sig2;
  float inv2ell = 1.0f / (2.0f * ell);
  float cj = (float)cnt[j];
  const float* drow = dist + (size_t)j * Q;
  float* grow = G + (size_t)j * Q;
  float s = 0.0f;
  for (int k = threadIdx.x; k < Q; k += 256) {
    float e = expf(-drow[k] * inv2ell);
    s += e * t[k];
    float g = sqrtf(cj * (float)cnt[k]) * (ratio * e);
    if (j == k) g += diag;
    grow[k] = g;
  }
  float tot = block_sum256(s, red);
  if (threadIdx.x == 0) {
    float wj = ratio * tot;
    z[j] = sqrtf(cj) * wj;          // b = W^{1/2} w
    atomicAdd(&scal[2], t[j] * wj); // t.w
  }
}

// ---------------------------------------------------------------------------
// One dispatch per Cholesky step. NO cross-block sync: the col-(j1) tile
// corrections are computed REDUNDANTLY by their consumers (r2/r7 lesson:
// in-kernel fences cost more than a kernel boundary on 8-XCD MI355X).
// j1 = column of the NEW panel being produced; j0 = j1-64 = previous panel.
// Roles by blockIdx (grid = 1 + m + m(m+1)/2 + m; m = trailing rowblocks):
//   bx == 0        : diag-z — corrected diag(j1) GEMM -> chol64 -> logdet
//                    -> z-sub(j1 block) -> solve z1(j1).
//   bx in [1, m]   : TRSM'' rowblock R0 = j1 + bx*64 — redundantly computes
//                    its own col-j1 correction (X_R X_j1^T) AND the corrected
//                    diag + chol64, then chain-solves its 64 rows.
//   next m(m+1)/2  : trailing 64x64 K=64 SYRK tiles over blocks >= j1+64
//                    (col-j1 tiles excluded — folded into TRSM'').
//   last m         : z forward-substitution for blocks >= j1+64.
// Prologue (j1 == 0): no corrections (G raw from build_mv), no tiles/z-jobs.
__global__ __launch_bounds__(256, 1) void estep(
    float* __restrict__ G, float* __restrict__ z, float* __restrict__ scal,
    int j1, int m, int ntile) {
  __shared__ __align__(16) float shA[64 * 68];   // X_j1 staging -> diagbuf
  __shared__ __align__(16) float shB[64 * 68];   // X_R staging  -> rowbuf
  __shared__ __align__(16) float LT[64 * 64];    // zero-padded L^T for chain
  __shared__ float invDs[64];
  __shared__ float z1s[64];
  __shared__ float z2s[64];
  int tid = threadIdx.x, bx = blockIdx.x;
  int lane = tid & 63;
  int j0 = j1 - 64;
  int tx = tid & 15, ty = tid >> 4;

  if (bx <= m) {
    bool isdiag = (bx == 0);
    int R0 = j1 + bx * 64;            // bx==0 -> the diag block itself

    if (j1 > 0) {
      // ---- phase A: stage panel-s operands (transposed, stride 68) ----
#pragma unroll
      for (int it = 0; it < 4; ++it) {
        int idx = it * 256 + tid;
        int r = idx >> 4, c4 = (idx & 15) * 4;
        float4 v = *(const float4*)(G + (size_t)(j1 + r) * Q + j0 + c4);
        shA[(c4 + 0) * 68 + r] = v.x; shA[(c4 + 1) * 68 + r] = v.y;
        shA[(c4 + 2) * 68 + r] = v.z; shA[(c4 + 3) * 68 + r] = v.w;
        if (!isdiag) {
          float4 u = *(const float4*)(G + (size_t)(R0 + r) * Q + j0 + c4);
          shB[(c4 + 0) * 68 + r] = u.x; shB[(c4 + 1) * 68 + r] = u.y;
          shB[(c4 + 2) * 68 + r] = u.z; shB[(c4 + 3) * 68 + r] = u.w;
        }
      }
      if (isdiag && tid < 64) z1s[tid] = z[j0 + tid];
      __syncthreads();

      // ---- phase B: correction GEMMs (K=64) ----
      float acc1[4][4] = {{0.f}};   // X_R  . X_j1^T  (rows correction)
      float acc2[4][4] = {{0.f}};   // X_j1 . X_j1^T  (diag correction)
#pragma unroll 8
      for (int p = 0; p < 64; ++p) {
        float4 a4 = *(const float4*)&shA[p * 68 + ty * 4];
        float4 b4 = *(const float4*)&shA[p * 68 + tx * 4];
        float av[4] = {a4.x, a4.y, a4.z, a4.w};
        float bv[4] = {b4.x, b4.y, b4.z, b4.w};
#pragma unroll
        for (int i = 0; i < 4; ++i)
#pragma unroll
          for (int jj = 0; jj < 4; ++jj) acc2[i][jj] += av[i] * bv[jj];
        if (!isdiag) {
          float4 c4v = *(const float4*)&shB[p * 68 + ty * 4];
          float cv[4] = {c4v.x, c4v.y, c4v.z, c4v.w};
#pragma unroll
          for (int i = 0; i < 4; ++i)
#pragma unroll
            for (int jj = 0; jj < 4; ++jj) acc1[i][jj] += cv[i] * bv[jj];
        }
      }
      // diag-z: z-sub for block j1 while shA still holds X_j1
      if (isdiag) {
        int rw = tid >> 2, part = tid & 3;
        float ssum = 0.f;
        for (int p = part; p < 64; p += 4) ssum += shA[p * 68 + rw] * z1s[p];
        ssum += __shfl_down(ssum, 2);
        ssum += __shfl_down(ssum, 1);
        if (part == 0) z2s[rw] = z[j1 + rw] - ssum;
      }
      __syncthreads();

      // ---- phase C: corrected tiles -> LDS (row-major; aliases shA/shB) ----
#pragma unroll
      for (int i = 0; i < 4; ++i) {
        float4 g = *(const float4*)(G + (size_t)(j1 + ty * 4 + i) * Q + j1 + tx * 4);
        shA[(ty * 4 + i) * 68 + tx * 4 + 0] = g.x - acc2[i][0];
        shA[(ty * 4 + i) * 68 + tx * 4 + 1] = g.y - acc2[i][1];
        shA[(ty * 4 + i) * 68 + tx * 4 + 2] = g.z - acc2[i][2];
        shA[(ty * 4 + i) * 68 + tx * 4 + 3] = g.w - acc2[i][3];
        if (!isdiag) {
          float4 h = *(const float4*)(G + (size_t)(R0 + ty * 4 + i) * Q + j1 + tx * 4);
          shB[(ty * 4 + i) * 68 + tx * 4 + 0] = h.x - acc1[i][0];
          shB[(ty * 4 + i) * 68 + tx * 4 + 1] = h.y - acc1[i][1];
          shB[(ty * 4 + i) * 68 + tx * 4 + 2] = h.z - acc1[i][2];
          shB[(ty * 4 + i) * 68 + tx * 4 + 3] = h.w - acc1[i][3];
        }
      }
      __syncthreads();
    } else {
      // ---- prologue: raw diag / raw rows, no corrections ----
#pragma unroll
      for (int it = 0; it < 4; ++it) {
        int idx = it * 256 + tid;
        int r = idx >> 4, c4 = (idx & 15) * 4;
        float4 g = *(const float4*)(G + (size_t)r * Q + c4);
        shA[r * 68 + c4 + 0] = g.x; shA[r * 68 + c4 + 1] = g.y;
        shA[r * 68 + c4 + 2] = g.z; shA[r * 68 + c4 + 3] = g.w;
        if (!isdiag) {
          float4 h = *(const float4*)(G + (size_t)(R0 + r) * Q + c4);
          shB[r * 68 + c4 + 0] = h.x; shB[r * 68 + c4 + 1] = h.y;
          shB[r * 68 + c4 + 2] = h.z; shB[r * 68 + c4 + 3] = h.w;
        }
      }
      if (isdiag && tid < 64) z2s[tid] = z[tid];
      __syncthreads();
    }

    // ---- wave0: factor corrected diag; then z-solve OR row-TRSM ----
    if (tid < 64) {
      float rr[64];
#pragma unroll
      for (int k4 = 0; k4 < 16; ++k4) {
        float4 v = *(const float4*)&shA[lane * 68 + k4 * 4];
        rr[k4 * 4 + 0] = v.x; rr[k4 * 4 + 1] = v.y;
        rr[k4 * 4 + 2] = v.z; rr[k4 * 4 + 3] = v.w;
      }
      __builtin_amdgcn_s_setprio(1);
      float dv = chol64_reg(rr, lane);
      __builtin_amdgcn_s_setprio(0);
      float myinv = 1.0f / dv;
      if (isdiag) {
        float lg = logf(dv);
#pragma unroll
        for (int o = 32; o > 0; o >>= 1) lg += __shfl_down(lg, o);
        if (lane == 0) atomicAdd(&scal[3], lg);
        // solve z1(j1): readlane chain with rr still live (round-4 proven)
        float a = z2s[lane];
#pragma unroll
        for (int p = 0; p < 64; ++p) {
          float xp = rl(a, p) * rl(myinv, p);
          if (lane > p) a -= xp * rr[p];
        }
        z[j1 + lane] = a * myinv;
      } else {
        invDs[lane] = myinv;
        // LT[p][k] = L[k][p] for p<k, else 0 (zero-pad -> float4 chain)
#pragma unroll
        for (int p = 0; p < 64; ++p)
          LT[p * 64 + lane] = (p < lane) ? rr[p] : 0.0f;
        // lane = row; chain-solve 64 rows vs LT (round-5 proven F2 pattern)
        float rr2[64];
#pragma unroll
        for (int k4 = 0; k4 < 16; ++k4) {
          float4 v = *(const float4*)&shB[lane * 68 + k4 * 4];
          rr2[k4 * 4 + 0] = v.x; rr2[k4 * 4 + 1] = v.y;
          rr2[k4 * 4 + 2] = v.z; rr2[k4 * 4 + 3] = v.w;
        }
        __builtin_amdgcn_s_setprio(1);
#pragma unroll
        for (int p = 0; p < 64; ++p) {
          float xp = rr2[p] * invDs[p];
          rr2[p] = xp;
#pragma unroll
          for (int k4 = 0; k4 < 16; ++k4) {
            if (k4 * 4 + 3 > p) {
              float4 l4 = *(const float4*)&LT[p * 64 + k4 * 4];
              rr2[k4 * 4 + 0] -= xp * l4.x;
              rr2[k4 * 4 + 1] -= xp * l4.y;
              rr2[k4 * 4 + 2] -= xp * l4.z;
              rr2[k4 * 4 + 3] -= xp * l4.w;
            }
          }
        }
        __builtin_amdgcn_s_setprio(0);
#pragma unroll
        for (int k4 = 0; k4 < 16; ++k4) {
          float4 st;
          st.x = rr2[k4 * 4 + 0]; st.y = rr2[k4 * 4 + 1];
          st.z = rr2[k4 * 4 + 2]; st.w = rr2[k4 * 4 + 3];
          *(float4*)(G + (size_t)(R0 + lane) * Q + j1 + k4 * 4) = st;
        }
      }
    }
    return;
  }

  // ---------------- trailing 64x64 K=64 SYRK tiles (cols >= j1+64) --------
  int tjob = bx - (m + 1);
  if (tjob < ntile) {
    int bi = (int)((sqrtf(8.0f * (float)tjob + 1.0f) - 1.0f) * 0.5f);
    while ((bi + 1) * (bi + 2) / 2 <= tjob) ++bi;
    while (bi * (bi + 1) / 2 > tjob) --bi;
    int bk = tjob - bi * (bi + 1) / 2;
    int R0 = j1 + 64 + bi * 64, C0 = j1 + 64 + bk * 64;
    bool sym = (bi == bk);
#pragma unroll
    for (int it = 0; it < 4; ++it) {
      int idx = it * 256 + tid;
      int r = idx >> 4, c4 = (idx & 15) * 4;
      float4 v = *(const float4*)(G + (size_t)(R0 + r) * Q + j0 + c4);
      shA[(c4 + 0) * 68 + r] = v.x; shA[(c4 + 1) * 68 + r] = v.y;
      shA[(c4 + 2) * 68 + r] = v.z; shA[(c4 + 3) * 68 + r] = v.w;
      if (!sym) {
        float4 u = *(const float4*)(G + (size_t)(C0 + r) * Q + j0 + c4);
        shB[(c4 + 0) * 68 + r] = u.x; shB[(c4 + 1) * 68 + r] = u.y;
        shB[(c4 + 2) * 68 + r] = u.z; shB[(c4 + 3) * 68 + r] = u.w;
      }
    }
    __syncthreads();
    const float* sB = sym ? shA : shB;
    float acc[4][4] = {{0.f}};
#pragma unroll 8
    for (int p = 0; p < 64; ++p) {
      float4 a4 = *(const float4*)&shA[p * 68 + ty * 4];
      float4 b4 = *(const float4*)&sB[p * 68 + tx * 4];
      float av[4] = {a4.x, a4.y, a4.z, a4.w};
      float bv[4] = {b4.x, b4.y, b4.z, b4.w};
#pragma unroll
      for (int i = 0; i < 4; ++i)
#pragma unroll
        for (int jj = 0; jj < 4; ++jj) acc[i][jj] += av[i] * bv[jj];
    }
#pragma unroll
    for (int i = 0; i < 4; ++i) {
      float* gp = G + (size_t)(R0 + ty * 4 + i) * Q + C0 + tx * 4;
      float4 g = *(const float4*)gp;
      g.x -= acc[i][0]; g.y -= acc[i][1];
      g.z -= acc[i][2]; g.w -= acc[i][3];
      *(float4*)gp = g;
    }
    return;
  }

  // ---------------- z-jobs: z[B0..] -= X_B(j0) . z1(j0) -------------------
  {
    int zb = tjob - ntile;
    int B0 = j1 + 64 + zb * 64;
    if (tid < 64) z1s[tid] = z[j0 + tid];
    __syncthreads();
    int rw = tid >> 2, part = tid & 3;
    const float* Lr = G + (size_t)(B0 + rw) * Q + j0;
    float ssum = 0.f;
    for (int p = part; p < 64; p += 4) ssum += Lr[p] * z1s[p];
    ssum += __shfl_down(ssum, 2);
    ssum += __shfl_down(ssum, 1);
    if (part == 0) z[B0 + rw] -= ssum;
  }
}

// ---------------------------------------------------------------------------
__global__ __launch_bounds__(256) void final_assemble(
    const float* __restrict__ z, const float* __restrict__ scal,
    const float* __restrict__ s2e_p, const float* __restrict__ s2b_p,
    float* __restrict__ out) {
  __shared__ float red[4];
  int tid = threadIdx.x;
  float bv = 0.f;
  for (int i = tid; i < Q; i += 256) {
    float zi = z[i];
    bv += zi * zi;
  }
  float bvs = block_sum256(bv, red);
  if (tid == 0) {
    float s2e = s2e_p[0], s2b = s2b_p[0];
    float sig2 = s2e + s2b;
    float c = s2e / sig2;
    float slp = scal[0], mtm = scal[1];
    float tw = scal[2], sl = scal[3];
    float tty = (tw - bvs) / c;          // t' y
    float mrm = (mtm - tty) / c;         // m' R^{-1} m
    float logdetR = (float)(NOBS - Q) * logf(c) + 2.0f * sl;
    out[0] = 0.5f * logdetR + 0.5f * mrm - 0.5f * mtm + 0.5f * slp;
  }
}

// ---------------------------------------------------------------------------
extern "C" void kernel_launch(void* const* d_in, const int* in_sizes, int n_in,
                              void* d_out, int out_size, void* d_ws, size_t ws_size,
                              hipStream_t stream) {
  const float* yt   = (const float*)d_in[0];
  const float* yp   = (const float*)d_in[1];
  const int*   zidx = (const int*)d_in[2];
  const float* dist = (const float*)d_in[3];
  const float* s2e  = (const float*)d_in[4];
  const float* s2b  = (const float*)d_in[5];
  const float* ell  = (const float*)d_in[6];

  float* ws   = (float*)d_ws;
  float* G    = ws;                         // Q*Q floats = 16 MB
  float* z    = ws + (size_t)Q * Q;         // Q
  float* t    = z + Q;                      // Q
  int*   cntv = (int*)(t + Q);              // Q ints
  float* scal = t + 2 * Q;                  // 8: slp, mtm, tw, sumlogL

  // zero t, cntv, scal
  hipMemsetAsync(t, 0, (2 * Q + 8) * sizeof(float), stream);

  obs_kernel<<<NOBS / 256, 256, 0, stream>>>(yt, yp, zidx, s2e, s2b, t, cntv, scal);
  build_mv<<<Q, 256, 0, stream>>>(dist, s2e, s2b, ell, cntv, t, G, z, scal);

  // prologue: factor block 0, solve z1(0), TRSM panel 0 (no corrections)
  estep<<<32, 256, 0, stream>>>(G, z, scal, 0, 31, 0);

  // one dispatch per step: tiles(s) [cols >= s+2] + TRSM''(s+1) + z
  for (int s = 0; s <= 30; ++s) {
    int j1 = (s + 1) * 64;
    int m = 30 - s;
    int ntile = m * (m + 1) / 2;
    estep<<<1 + 2 * m + ntile, 256, 0, stream>>>(G, z, scal, j1, m, ntile);
  }

  final_assemble<<<1, 256, 0, stream>>>(z, scal, s2e, s2b, (float*)d_out);
}

// Round 9
// 973.551 us; speedup vs baseline: 1.1290x; 1.1290x over previous
//
#include <hip/hip_runtime.h>
#include <math.h>

#define Q 2048
#define NOBS 8192

// ---------------------------------------------------------------------------
// readlane broadcast (lane index literal after unroll): VALU->SGPR, no LDS.
__device__ __forceinline__ float rl(float v, int l) {
  return __int_as_float(__builtin_amdgcn_readlane(__float_as_int(v), l));
}

// ---------------------------------------------------------------------------
__device__ __forceinline__ float block_sum256(float v, volatile float* red) {
  int tid = threadIdx.x;
#pragma unroll
  for (int o = 32; o > 0; o >>= 1) v += __shfl_down(v, o);
  __syncthreads();
  if ((tid & 63) == 0) red[tid >> 6] = v;
  __syncthreads();
  return red[0] + red[1] + red[2] + red[3];
}

// ---------------------------------------------------------------------------
// In-register 64x64 Cholesky, one wave, lane = row (round-3/4 proven).
// rr[64] MUST stay in VGPRs (spill = 25x slowdown, measured round 3).
__device__ __forceinline__ float chol64_reg(float rr[64], int lane) {
  float dv = 1.0f;
#pragma unroll
  for (int j = 0; j < 64; ++j) {
    float vjj = rl(rr[j], j);
    float invd = rsqrtf(vjj);
    float lij = rr[j] * invd;   // lane j gets sqrt(vjj)
    rr[j] = lij;
    if (lane == j) dv = lij;
#pragma unroll
    for (int k = j + 1; k < 64; ++k) rr[k] -= lij * rl(lij, k);
  }
  return dv;
}

// ---------------------------------------------------------------------------
// Solve X L^T = A in place on a transposed LDS tile (sh[c*68+r] = A[r][c]).
// One wave, lane = row, rows in registers vs zero-padded LT (round-5 proven).
__device__ __forceinline__ void panel_solve(float* sh, const float* LT,
                                            const float* invDs, int lane) {
  float rr2[64];
#pragma unroll
  for (int k = 0; k < 64; ++k) rr2[k] = sh[k * 68 + lane];
  __builtin_amdgcn_s_setprio(1);
#pragma unroll
  for (int p = 0; p < 64; ++p) {
    float xp = rr2[p] * invDs[p];
    rr2[p] = xp;
#pragma unroll
    for (int k4 = 0; k4 < 16; ++k4) {
      if (k4 * 4 + 3 > p) {          // chunks fully <= p are zero-padded
        float4 l4 = *(const float4*)&LT[p * 64 + k4 * 4];
        rr2[k4 * 4 + 0] -= xp * l4.x;
        rr2[k4 * 4 + 1] -= xp * l4.y;
        rr2[k4 * 4 + 2] -= xp * l4.z;
        rr2[k4 * 4 + 3] -= xp * l4.w;
      }
    }
  }
  __builtin_amdgcn_s_setprio(0);
#pragma unroll
  for (int k = 0; k < 64; ++k) sh[k * 68 + lane] = rr2[k];
}

// ---------------------------------------------------------------------------
// Solve L y = zin (single rhs) via register row copy + readlane chain
// (round-4 proven). Result -> z1s[lane].
__device__ __forceinline__ void zsolve(const float* LT, const float* invDs,
                                       const float* zin, float* z1s, int lane) {
  float rr3[64];
#pragma unroll
  for (int p = 0; p < 64; ++p) rr3[p] = LT[p * 64 + lane];  // L[lane][p], 0-pad
  float a = zin[lane];
  float myinv = invDs[lane];
#pragma unroll
  for (int p = 0; p < 64; ++p) {
    float xp = rl(a, p) * rl(myinv, p);
    if (lane > p) a -= xp * rr3[p];
  }
  z1s[lane] = a * myinv;
}

// ---------------------------------------------------------------------------
__global__ __launch_bounds__(256) void obs_kernel(
    const float* __restrict__ yt, const float* __restrict__ yp,
    const int* __restrict__ zidx, const float* __restrict__ s2e_p,
    const float* __restrict__ s2b_p, float* __restrict__ t,
    int* __restrict__ cnt, float* __restrict__ scal) {
  __shared__ float red[4];
  int i = blockIdx.x * 256 + threadIdx.x;
  float s2e = s2e_p[0], s2b = s2b_p[0];
  float sig2 = s2e + s2b;
  float r = yt[i] - yp[i];
  float e = erff(r * rsqrtf(2.0f * sig2));
  float u = 0.5f * (e + 1.0f);
  u = fminf(fmaxf(u, 1e-5f), 1.0f - 1e-5f);
  float m = erfinvf(2.0f * u - 1.0f) * 1.4142135623730951f;
  float slp = -0.5f * logf(2.0f * 3.14159265358979f * sig2) - r * r / (2.0f * sig2);
  int z = zidx[i];
  atomicAdd(&t[z], m);
  atomicAdd(&cnt[z], 1);
  float s1 = block_sum256(slp, red);
  float s2 = block_sum256(m * m, red);
  if (threadIdx.x == 0) {
    atomicAdd(&scal[0], s1);   // sum_log_pdf
    atomicAdd(&scal[1], s2);   // m'm
  }
}

// ---------------------------------------------------------------------------
// Fused: build G row j AND the matvec w = K t in one pass over dist row j.
__global__ __launch_bounds__(256) void build_mv(
    const float* __restrict__ dist, const float* __restrict__ s2e_p,
    const float* __restrict__ s2b_p, const float* __restrict__ ell_p,
    const int* __restrict__ cnt, const float* __restrict__ t,
    float* __restrict__ G, float* __restrict__ z, float* __restrict__ scal) {
  __shared__ float red[4];
  int j = blockIdx.x;
  float s2e = s2e_p[0], s2b = s2b_p[0], ell = ell_p[0];
  float sig2 = s2e + s2b;
  float ratio = s2b / sig2;
  float diag = s2e / sig2;
  float inv2ell = 1.0f / (2.0f * ell);
  float cj = (float)cnt[j];
  const float* drow = dist + (size_t)j * Q;
  float* grow = G + (size_t)j * Q;
  float s = 0.0f;
  for (int k = threadIdx.x; k < Q; k += 256) {
    float e = expf(-drow[k] * inv2ell);
    s += e * t[k];
    float g = sqrtf(cj * (float)cnt[k]) * (ratio * e);
    if (j == k) g += diag;
    grow[k] = g;
  }
  float tot = block_sum256(s, red);
  if (threadIdx.x == 0) {
    float wj = ratio * tot;
    z[j] = sqrtf(cj) * wj;          // b = W^{1/2} w
    atomicAdd(&scal[2], t[j] * wj); // t.w
  }
}

// ---------------------------------------------------------------------------
// Factor G(0,0) into dsA; accumulate logdet. Single wave, full VGPR budget.
__global__ __launch_bounds__(64, 1) void potrf_first(
    const float* __restrict__ G, float* __restrict__ dsA,
    float* __restrict__ scal) {
  int lane = threadIdx.x;
  float rr[64];
  const float* row = G + (size_t)lane * Q;
#pragma unroll
  for (int k4 = 0; k4 < 16; ++k4) {
    float4 v = *(const float4*)(row + k4 * 4);
    rr[k4 * 4 + 0] = v.x; rr[k4 * 4 + 1] = v.y;
    rr[k4 * 4 + 2] = v.z; rr[k4 * 4 + 3] = v.w;
  }
  float dv = chol64_reg(rr, lane);
#pragma unroll
  for (int k4 = 0; k4 < 16; ++k4) {
    float4 st;
    st.x = rr[k4 * 4 + 0]; st.y = rr[k4 * 4 + 1];
    st.z = rr[k4 * 4 + 2]; st.w = rr[k4 * 4 + 3];
    *(float4*)(dsA + lane * 64 + k4 * 4) = st;
  }
  float lg = logf(dv);
#pragma unroll
  for (int o = 32; o > 0; o >>= 1) lg += __shfl_down(lg, o);
  if (lane == 0) atomicAdd(&scal[3], lg);
}

// ---------------------------------------------------------------------------
// ONE dispatch per Cholesky step s (j0 = s*64). L is never stored: every
// consumer chain-solves the panel rows it needs from the UPDATED G and the
// staged diag factor dsR (solve = ~1.5us/wave, r5-proven; cheaper than a
// TRSM dispatch + gap, r4-r8 measured). No cross-block deps; kernel boundary
// is the only sync (r2/r7 lesson: in-kernel fences cost more).
//   bx == 0 (job0): solve X_{s+1}; D' = G(s+1,s+1) - X X^T; chol64 -> dsW;
//                   logdet; solve z1(s) -> z1[]; z(s+1) -= X z1(s).
//   tjob = bx-1 in [1, ntile): trailing tile (bi,bk), blocks >= s+1:
//                   solve X_bi, X_bk from G cols s; G(bi,bk) -= X_bi X_bk^T;
//                   sym tiles also do z(bi) -= X_bi z1(s) (z1 self-solved).
//   tjob == 0 ((s+1,s+1)): dead block — job0 owns that tile.
__global__ __launch_bounds__(256, 1) void estep(
    float* __restrict__ G, float* __restrict__ z, float* __restrict__ z1,
    float* __restrict__ scal, const float* __restrict__ dsR,
    float* __restrict__ dsW, int j0) {
  __shared__ __align__(16) float shA[64 * 68];
  __shared__ __align__(16) float shB[64 * 68];
  __shared__ __align__(16) float LT[64 * 64];
  __shared__ float invDs[64];
  __shared__ float z1s[64];
  int tid = threadIdx.x, bx = blockIdx.x;
  int lane = tid & 63, wv = tid >> 6;
  int tx = tid & 15, ty = tid >> 4;
  int j1 = j0 + 64;

  bool isjob0 = (bx == 0);
  int tjob = bx - 1;
  if (!isjob0 && tjob == 0) return;   // (s+1,s+1): job0's tile

  int R0, C0;
  bool sym;
  if (isjob0) {
    R0 = j1; C0 = j1; sym = true;
  } else {
    int bi = (int)((sqrtf(8.0f * (float)tjob + 1.0f) - 1.0f) * 0.5f);
    while ((bi + 1) * (bi + 2) / 2 <= tjob) ++bi;
    while (bi * (bi + 1) / 2 > tjob) --bi;
    int bk = tjob - bi * (bi + 1) / 2;
    R0 = j1 + bi * 64; C0 = j1 + bk * 64; sym = (bi == bk);
  }

  // ---- stage LT (zero-padded strictly-lower L^T) + invDs from dsR ----
#pragma unroll
  for (int it = 0; it < 4; ++it) {
    int idx = it * 256 + tid;
    int r = idx >> 4, c4 = (idx & 15) * 4;
    float4 v = *(const float4*)(dsR + r * 64 + c4);
    LT[(c4 + 0) * 64 + r] = (c4 + 0 < r) ? v.x : 0.0f;
    LT[(c4 + 1) * 64 + r] = (c4 + 1 < r) ? v.y : 0.0f;
    LT[(c4 + 2) * 64 + r] = (c4 + 2 < r) ? v.z : 0.0f;
    LT[(c4 + 3) * 64 + r] = (c4 + 3 < r) ? v.w : 0.0f;
    if (r >= c4 && r < c4 + 4) {
      float d = (r == c4) ? v.x : (r == c4 + 1) ? v.y : (r == c4 + 2) ? v.z : v.w;
      invDs[r] = 1.0f / d;
    }
  }
  // ---- stage A^T tiles (G rows, panel col j0) — r4-proven coalesced ----
#pragma unroll
  for (int it = 0; it < 4; ++it) {
    int idx = it * 256 + tid;
    int r = idx >> 4, c4 = (idx & 15) * 4;
    float4 v = *(const float4*)(G + (size_t)(R0 + r) * Q + j0 + c4);
    shA[(c4 + 0) * 68 + r] = v.x; shA[(c4 + 1) * 68 + r] = v.y;
    shA[(c4 + 2) * 68 + r] = v.z; shA[(c4 + 3) * 68 + r] = v.w;
    if (!sym) {
      float4 u = *(const float4*)(G + (size_t)(C0 + r) * Q + j0 + c4);
      shB[(c4 + 0) * 68 + r] = u.x; shB[(c4 + 1) * 68 + r] = u.y;
      shB[(c4 + 2) * 68 + r] = u.z; shB[(c4 + 3) * 68 + r] = u.w;
    }
  }
  __syncthreads();

  // ---- solves: wave0 = X_bi (in place); wave1 = X_bk or z1(s) ----
  if (wv == 0) {
    panel_solve(shA, LT, invDs, lane);
  } else if (wv == 1) {
    if (!sym) panel_solve(shB, LT, invDs, lane);
    else      zsolve(LT, invDs, z + j0, z1s, lane);
  }
  __syncthreads();

  if (isjob0 && wv == 1) z1[j0 + lane] = z1s[lane];   // publish z1(s)

  // ---- GEMM: acc = X_bi . X_bk^T (K=64) ----
  const float* sB = sym ? shA : shB;
  float acc[4][4] = {{0.f}};
#pragma unroll 8
  for (int p = 0; p < 64; ++p) {
    float4 a4 = *(const float4*)&shA[p * 68 + ty * 4];
    float4 b4 = *(const float4*)&sB[p * 68 + tx * 4];
    float av[4] = {a4.x, a4.y, a4.z, a4.w};
    float bv[4] = {b4.x, b4.y, b4.z, b4.w};
#pragma unroll
    for (int i = 0; i < 4; ++i)
#pragma unroll
      for (int jj = 0; jj < 4; ++jj) acc[i][jj] += av[i] * bv[jj];
  }

  if (isjob0) {
    // D' = G(j1,j1) - acc -> shB row-major (stride 68)
#pragma unroll
    for (int i = 0; i < 4; ++i) {
      const float* gp = G + (size_t)(j1 + ty * 4 + i) * Q + j1 + tx * 4;
      float4 g = *(const float4*)gp;
      shB[(ty * 4 + i) * 68 + tx * 4 + 0] = g.x - acc[i][0];
      shB[(ty * 4 + i) * 68 + tx * 4 + 1] = g.y - acc[i][1];
      shB[(ty * 4 + i) * 68 + tx * 4 + 2] = g.z - acc[i][2];
      shB[(ty * 4 + i) * 68 + tx * 4 + 3] = g.w - acc[i][3];
    }
    __syncthreads();
    if (wv == 0) {
      // factor D' -> dsW, logdet
      float rr[64];
#pragma unroll
      for (int k4 = 0; k4 < 16; ++k4) {
        float4 v = *(const float4*)&shB[lane * 68 + k4 * 4];
        rr[k4 * 4 + 0] = v.x; rr[k4 * 4 + 1] = v.y;
        rr[k4 * 4 + 2] = v.z; rr[k4 * 4 + 3] = v.w;
      }
      __builtin_amdgcn_s_setprio(1);
      float dv = chol64_reg(rr, lane);
      __builtin_amdgcn_s_setprio(0);
#pragma unroll
      for (int k4 = 0; k4 < 16; ++k4) {
        float4 st;
        st.x = rr[k4 * 4 + 0]; st.y = rr[k4 * 4 + 1];
        st.z = rr[k4 * 4 + 2]; st.w = rr[k4 * 4 + 3];
        *(float4*)(dsW + lane * 64 + k4 * 4) = st;
      }
      float lg = logf(dv);
#pragma unroll
      for (int o = 32; o > 0; o >>= 1) lg += __shfl_down(lg, o);
      if (lane == 0) atomicAdd(&scal[3], lg);
    } else if (wv == 1) {
      // z(s+1) -= X_{s+1} . z1(s)   (shA, z1s stable since solve-sync)
      float zs = 0.f;
#pragma unroll 8
      for (int p = 0; p < 64; ++p) zs += shA[p * 68 + lane] * z1s[p];
      z[j1 + lane] -= zs;
    }
    return;
  }

  // ---- tiles: sym also applies the z reduction for its block ----
  if (sym && wv == 0) {
    float zs = 0.f;
#pragma unroll 8
    for (int p = 0; p < 64; ++p) zs += shA[p * 68 + lane] * z1s[p];
    z[R0 + lane] -= zs;
  }
#pragma unroll
  for (int i = 0; i < 4; ++i) {
    float* gp = G + (size_t)(R0 + ty * 4 + i) * Q + C0 + tx * 4;
    float4 g = *(const float4*)gp;
    g.x -= acc[i][0]; g.y -= acc[i][1];
    g.z -= acc[i][2]; g.w -= acc[i][3];
    *(float4*)gp = g;
  }
}

// ---------------------------------------------------------------------------
// Solve the last block z1(31) from ds31 + z2(31), then assemble the loss.
__global__ __launch_bounds__(256) void final_assemble(
    const float* __restrict__ z, const float* __restrict__ z1,
    const float* __restrict__ ds31, const float* __restrict__ scal,
    const float* __restrict__ s2e_p, const float* __restrict__ s2b_p,
    float* __restrict__ out) {
  __shared__ float red[4];
  __shared__ float z1last[64];
  int tid = threadIdx.x;
  if (tid < 64) {
    int lane = tid;
    float rr3[64];
#pragma unroll
    for (int k4 = 0; k4 < 16; ++k4) {
      float4 v = *(const float4*)(ds31 + lane * 64 + k4 * 4);
      rr3[k4 * 4 + 0] = v.x; rr3[k4 * 4 + 1] = v.y;
      rr3[k4 * 4 + 2] = v.z; rr3[k4 * 4 + 3] = v.w;
    }
    float myinv = 1.0f / rr3[lane];
    float a = z[Q - 64 + lane];
#pragma unroll
    for (int p = 0; p < 64; ++p) {
      float xp = rl(a, p) * rl(myinv, p);
      if (lane > p) a -= xp * rr3[p];
    }
    z1last[lane] = a * myinv;
  }
  __syncthreads();
  float bv = 0.f;
  for (int i = tid; i < Q; i += 256) {
    float zi = (i < Q - 64) ? z1[i] : z1last[i - (Q - 64)];
    bv += zi * zi;
  }
  float bvs = block_sum256(bv, red);
  if (tid == 0) {
    float s2e = s2e_p[0], s2b = s2b_p[0];
    float sig2 = s2e + s2b;
    float c = s2e / sig2;
    float slp = scal[0], mtm = scal[1];
    float tw = scal[2], sl = scal[3];
    float tty = (tw - bvs) / c;          // t' y
    float mrm = (mtm - tty) / c;         // m' R^{-1} m
    float logdetR = (float)(NOBS - Q) * logf(c) + 2.0f * sl;
    out[0] = 0.5f * logdetR + 0.5f * mrm - 0.5f * mtm + 0.5f * slp;
  }
}

// ---------------------------------------------------------------------------
extern "C" void kernel_launch(void* const* d_in, const int* in_sizes, int n_in,
                              void* d_out, int out_size, void* d_ws, size_t ws_size,
                              hipStream_t stream) {
  const float* yt   = (const float*)d_in[0];
  const float* yp   = (const float*)d_in[1];
  const int*   zidx = (const int*)d_in[2];
  const float* dist = (const float*)d_in[3];
  const float* s2e  = (const float*)d_in[4];
  const float* s2b  = (const float*)d_in[5];
  const float* ell  = (const float*)d_in[6];

  float* ws   = (float*)d_ws;
  float* G    = ws;                         // Q*Q floats = 16 MB
  float* z    = ws + (size_t)Q * Q;         // Q (running-reduced z2 values)
  float* t    = z + Q;                      // Q
  int*   cntv = (int*)(t + Q);              // Q ints
  float* scal = t + 2 * Q;                  // 8: slp, mtm, tw, sumlogL
  float* z1   = scal + 8;                   // Q (solved y = L^{-1} b)
  float* dsA  = z1 + Q;                     // 64*64 staged diag factor (even s)
  float* dsB  = dsA + 4096;                 // 64*64 staged diag factor (odd s)

  // zero t, cntv, scal
  hipMemsetAsync(t, 0, (2 * Q + 8) * sizeof(float), stream);

  obs_kernel<<<NOBS / 256, 256, 0, stream>>>(yt, yp, zidx, s2e, s2b, t, cntv, scal);
  build_mv<<<Q, 256, 0, stream>>>(dist, s2e, s2b, ell, cntv, t, G, z, scal);

  potrf_first<<<1, 64, 0, stream>>>(G, dsA, scal);

  // one dispatch per step: consumers self-solve panels (no TRSM dispatch)
  for (int s = 0; s <= 30; ++s) {
    int m = 31 - s;
    int ntile = m * (m + 1) / 2;
    const float* dsR = (s & 1) ? dsB : dsA;
    float* dsW = (s & 1) ? dsA : dsB;
    estep<<<1 + ntile, 256, 0, stream>>>(G, z, z1, scal, dsR, dsW, s * 64);
  }

  final_assemble<<<1, 256, 0, stream>>>(z, z1, dsB, scal, s2e, s2b,
                                        (float*)d_out);
}